// Round 1
// 2049.069 us; speedup vs baseline: 1.3779x; 1.3779x over previous
//
#include <hip/hip_runtime.h>
#include <hip/hip_bf16.h>
#include <math.h>

// Problem constants
#define UN 4096      // units
#define DN 1024      // model dim
#define LN_ 4        // layers
#define HN 16        // heads
#define HD 64        // head dim

typedef __attribute__((ext_vector_type(8))) short bf16x8;   // 8 bf16 = 4 VGPRs
typedef __attribute__((ext_vector_type(4))) float f32x4;

// float -> bf16 bits, round-to-nearest-even
__device__ __forceinline__ short f2bf(float f) {
  union { float f; unsigned u; } x; x.f = f;
  unsigned r = x.u + 0x7fffu + ((x.u >> 16) & 1u);
  return (short)(r >> 16);
}
__device__ __forceinline__ float bf2f(short b) {
  union { unsigned u; float f; } x; x.u = ((unsigned)(unsigned short)b) << 16;
  return x.f;
}

// async global->LDS, 16B per lane. LDS dest = wave-uniform base + lane*16.
__device__ __forceinline__ void gload16(const void* g, void* l) {
  __builtin_amdgcn_global_load_lds(
      (const __attribute__((address_space(1))) void*)g,
      (__attribute__((address_space(3))) void*)l, 16, 0, 0);
}

// ---------------------------------------------------------------------------
// fp32 -> bf16 weight conversion (contiguous), 8 elts/thread
// ---------------------------------------------------------------------------
__global__ __launch_bounds__(256)
void convw_kernel(const float* __restrict__ src, short* __restrict__ dst)
{
  int i = blockIdx.x * 256 + threadIdx.x;           // handles elements [8i, 8i+8)
  float4 f0 = ((const float4*)src)[i * 2];
  float4 f1 = ((const float4*)src)[i * 2 + 1];
  bf16x8 o;
  o[0] = f2bf(f0.x); o[1] = f2bf(f0.y); o[2] = f2bf(f0.z); o[3] = f2bf(f0.w);
  o[4] = f2bf(f1.x); o[5] = f2bf(f1.y); o[6] = f2bf(f1.z); o[7] = f2bf(f1.w);
  ((bf16x8*)dst)[i] = o;
}

// in_w is [1024][1025]; repack first 1024 cols to bf16 [1024][1024]
__global__ __launch_bounds__(256)
void convw_in_kernel(const float* __restrict__ src, short* __restrict__ dst)
{
  int idx = blockIdx.x * 256 + threadIdx.x;         // < 1024*1024
  int r = idx >> 10, c = idx & 1023;
  dst[idx] = f2bf(src[r * 1025 + c]);
}

// ---------------------------------------------------------------------------
// bf16 MFMA GEMM (m97 structure): C[m][n] = act( sum_k A[m][k]*W[n][k] + bias[n]
//                                               [+ ent[m]*wcol[n]] )
// A: M x K bf16 (lda). W: N x K bf16 (ldw) — pre-converted.
// Staging via global_load_lds width=16 into LINEAR LDS (no pad; m97 parity).
// TM=128: tile 128x128, 4 waves 2x2 of 64x64, acc 4x4.
// TM=64 : tile  64x128, 4 waves 2x2 of 32x64, acc 2x4  (2x grid for N<=1024).
// M%TM==0, N%128==0, K%32==0, lda/ldw multiples of 8 (16B rows).
// ---------------------------------------------------------------------------
template<int TM>
__global__ __launch_bounds__(256)
void gemm_bf16(const short* __restrict__ A, int lda,
               const short* __restrict__ W, int ldw,
               const float* __restrict__ bias,
               float* __restrict__ C32, short* __restrict__ C16, int ldc,
               int K, int relu,
               const float* __restrict__ ent, const float* __restrict__ wcol,
               int wstride)
{
  constexpr int MBF = TM / 32;      // M-frags per wave: 4 or 2
  constexpr int AIN = TM / 64;      // A gload insts per wave: 2 or 1
  __shared__ __align__(16) short As[TM][32];
  __shared__ __align__(16) short Ws[128][32];

  const int tid  = threadIdx.x;
  const int bm = blockIdx.x, bn = blockIdx.y;
  const int lane = tid & 63, wave = tid >> 6;
  const int n = lane & 15, quad = lane >> 4;
  const int mw = (wave >> 1) * (TM / 2), nw = (wave & 1) * 64;

  f32x4 acc[MBF][4];
#pragma unroll
  for (int mb = 0; mb < MBF; mb++)
#pragma unroll
    for (int nb = 0; nb < 4; nb++)
#pragma unroll
      for (int r = 0; r < 4; r++) acc[mb][nb][r] = 0.f;

  // staging map: per gload inst a wave writes 1024B = 16 rows x 64B.
  // lane l -> row base + (l>>2), 16B chunk (l&3)  (LDS linear row-major).
  const int sr = lane >> 2;
  const int sc = (lane & 3) * 8;
  const short* aSrc[AIN]; short* aDst[AIN];
#pragma unroll
  for (int i = 0; i < AIN; i++) {
    aSrc[i] = A + (size_t)(bm * TM + wave * (16 * AIN) + i * 16 + sr) * lda + sc;
    aDst[i] = &As[wave * (16 * AIN) + i * 16][0];
  }
  const short* wSrc[2]; short* wDst[2];
#pragma unroll
  for (int i = 0; i < 2; i++) {
    wSrc[i] = W + (size_t)(bn * 128 + wave * 32 + i * 16 + sr) * ldw + sc;
    wDst[i] = &Ws[wave * 32 + i * 16][0];
  }

  for (int kk = 0; kk < K; kk += 32) {
    __syncthreads();              // all waves done reading previous tile
#pragma unroll
    for (int i = 0; i < AIN; i++) gload16(aSrc[i] + kk, aDst[i]);
#pragma unroll
    for (int i = 0; i < 2; i++)   gload16(wSrc[i] + kk, wDst[i]);
    __syncthreads();              // vmcnt(0) drain + barrier: tile ready

    bf16x8 af[MBF], bfr[4];
#pragma unroll
    for (int mb = 0; mb < MBF; mb++) af[mb] = *(bf16x8*)&As[mw + mb * 16 + n][quad * 8];
#pragma unroll
    for (int nb = 0; nb < 4; nb++)   bfr[nb] = *(bf16x8*)&Ws[nw + nb * 16 + n][quad * 8];
#pragma unroll
    for (int mb = 0; mb < MBF; mb++)
#pragma unroll
      for (int nb = 0; nb < 4; nb++)
        acc[mb][nb] = __builtin_amdgcn_mfma_f32_16x16x32_bf16(af[mb], bfr[nb], acc[mb][nb], 0, 0, 0);
  }

  // ---- epilogue (MFMA C-layout: row = quad*4+r, col = n within 16x16) ----
#pragma unroll
  for (int mb = 0; mb < MBF; mb++) {
    float entv[4];
#pragma unroll
    for (int r = 0; r < 4; r++)
      entv[r] = ent ? ent[bm * TM + mw + mb * 16 + quad * 4 + r] : 0.f;
#pragma unroll
    for (int nb = 0; nb < 4; nb++) {
      const int col = bn * 128 + nw + nb * 16 + n;
      const float bs = bias[col];
      const float wc = ent ? wcol[(size_t)col * wstride] : 0.f;
#pragma unroll
      for (int r = 0; r < 4; r++) {
        const int row = bm * TM + mw + mb * 16 + quad * 4 + r;
        float v = acc[mb][nb][r] + bs;
        if (ent)  v += entv[r] * wc;
        if (relu) v = fmaxf(v, 0.f);
        if (C32) C32[(size_t)row * ldc + col] = v;
        if (C16) C16[(size_t)row * ldc + col] = f2bf(v);
      }
    }
  }
}

// ---------------------------------------------------------------------------
// gather + fp32->bf16: dst[u][k] = bf16(node_emb[ids[u]][k])
// ---------------------------------------------------------------------------
__global__ __launch_bounds__(256)
void gather_conv_kernel(const float* __restrict__ emb, const int* __restrict__ ids,
                        short* __restrict__ dst)
{
  int idx = blockIdx.x * 256 + threadIdx.x;   // < UN*DN
  int u = idx >> 10;
  dst[idx] = f2bf(emb[(size_t)ids[u] * 1024 + (idx & 1023)]);
}

// ---------------------------------------------------------------------------
// RoPE: reads X fp32, writes bf16 xr
// ---------------------------------------------------------------------------
__global__ __launch_bounds__(256)
void rope_kernel(const float* __restrict__ x, short* __restrict__ xr,
                 const int* __restrict__ ids, const int* __restrict__ nyp)
{
  int idx = blockIdx.x * 256 + threadIdx.x;
  int u = idx >> 10, j = idx & 1023;
  int blk = j >> 9, o = j & 511;
  int i = o & 255;
  int t = ids[u];
  int ny = *nyp;
  float pos = (blk == 0) ? (float)(t / ny) : (float)(t % ny);
  float theta = expf((float)i * -0.0359778921f);   // -ln(10000)/256
  float ang = pos * theta;
  float c = cosf(ang), sn = sinf(ang);
  const float* xrow = x + (size_t)u * 1024 + blk * 512;
  float x1 = xrow[i];
  float x2 = xrow[256 + i];
  xr[idx] = f2bf((o < 256) ? (x1 * c - x2 * sn) : (x1 * sn + x2 * c));
}

// ---------------------------------------------------------------------------
// MFMA bf16 flash attention (bf16 in / bf16 out).
// qk: bf16 [4096][2048] fused q|k; v: bf16 [4096][1024]; o: bf16 [4096][1024].
// Changes vs prev round:
//  - Kt/Vt/Pb rows are 128 B (64 shorts), XOR-swizzled: phys_byte =
//    logical_byte ^ ((row&7)<<4). Kills the stride-36-word 8-way conflicts.
//  - P fp32->bf16 via v_cvt_pk_bf16_f32 pairs (RNE, same rounding as f2bf).
//  - defer-max (THR=8): skip max-reduce shfls + rescale when no lane's local
//    tile max exceeds m+8; P bounded by e^8, fp32 l/o accum absorbs it.
// ---------------------------------------------------------------------------
__global__ __launch_bounds__(256)
void attn_mfma_kernel(const short* __restrict__ qk, const short* __restrict__ v,
                      short* __restrict__ o)
{
  __shared__ __align__(16) short Kt[64][64];        // [key][d]  swizzled
  __shared__ __align__(16) short Vt[64][64];        // [d][key]  swizzled
  __shared__ __align__(16) short Pb[4][16][64];     // per-wave P slab, swizzled

  const int tid  = threadIdx.x;
  const int lane = tid & 63;
  const int wave = tid >> 6;
  const int head = blockIdx.y;
  const int qb   = blockIdx.x;

  const int n    = lane & 15;
  const int quad = lane >> 4;

  // Q fragments: row = qb*64 + wave*16 + n ; scale 1/8 exact (pow2)
  bf16x8 qfrag[2];
  {
    const int qrow = qb * 64 + wave * 16 + n;
    const short* qptr = qk + (size_t)qrow * 2048 + head * 64 + quad * 8;
#pragma unroll
    for (int c = 0; c < 2; c++)
#pragma unroll
      for (int j = 0; j < 8; j++)
        qfrag[c][j] = f2bf(bf2f(qptr[c * 32 + j]) * 0.125f);
  }

  float m_r[4], l_r[4];
  f32x4 o_acc[4];
#pragma unroll
  for (int r = 0; r < 4; r++) { m_r[r] = -3.0e38f; l_r[r] = 0.f; }
#pragma unroll
  for (int nb = 0; nb < 4; nb++)
#pragma unroll
    for (int r = 0; r < 4; r++) o_acc[nb][r] = 0.f;

  const int skey = tid & 63;          // staging: key row
  const int sd0  = wave * 16;         // staging: d-chunk
  const int krx  = (skey & 7) << 4;   // Kt store swizzle for this thread

  char* KtB = (char*)&Kt[0][0];
  char* VtB = (char*)&Vt[0][0];
  char* PbB = (char*)&Pb[wave][0][0];

  for (int kt = 0; kt < 64; kt++) {
    __syncthreads();
    {
      const short* kp = qk + (size_t)(kt * 64 + skey) * 2048 + 1024 + head * 64 + sd0;
      bf16x8 k0 = *(const bf16x8*)(kp);
      bf16x8 k1 = *(const bf16x8*)(kp + 8);
      *(bf16x8*)(KtB + skey * 128 + ((sd0 * 2)      ^ krx)) = k0;
      *(bf16x8*)(KtB + skey * 128 + ((sd0 * 2 + 16) ^ krx)) = k1;
      const short* vp = v + (size_t)(kt * 64 + skey) * 1024 + head * 64 + sd0;
      bf16x8 v0 = *(const bf16x8*)(vp);
      bf16x8 v1 = *(const bf16x8*)(vp + 8);
#pragma unroll
      for (int i = 0; i < 8; i++) {
        int d = sd0 + i;
        *(short*)(VtB + d * 128 + ((2 * skey) ^ ((d & 7) << 4))) = v0[i];
      }
#pragma unroll
      for (int i = 0; i < 8; i++) {
        int d = sd0 + 8 + i;
        *(short*)(VtB + d * 128 + ((2 * skey) ^ ((d & 7) << 4))) = v1[i];
      }
    }
    __syncthreads();

    // ---- QK^T ----
    f32x4 s[4];
#pragma unroll
    for (int nb = 0; nb < 4; nb++) {
      const int row = nb * 16 + n;
      const int rx = (row & 7) << 4;
      bf16x8 k0 = *(bf16x8*)(KtB + row * 128 + ((quad * 16)      ^ rx));
      bf16x8 k1 = *(bf16x8*)(KtB + row * 128 + ((64 + quad * 16) ^ rx));
      f32x4 z = {0.f, 0.f, 0.f, 0.f};
      z = __builtin_amdgcn_mfma_f32_16x16x32_bf16(qfrag[0], k0, z, 0, 0, 0);
      z = __builtin_amdgcn_mfma_f32_16x16x32_bf16(qfrag[1], k1, z, 0, 0, 0);
      s[nb] = z;
    }

    // ---- online softmax with deferred max (THR=8) ----
    float tl[4];
#pragma unroll
    for (int r = 0; r < 4; r++)
      tl[r] = fmaxf(fmaxf(s[0][r], s[1][r]), fmaxf(s[2][r], s[3][r]));
    bool grow = (tl[0] > m_r[0] + 8.f) || (tl[1] > m_r[1] + 8.f) ||
                (tl[2] > m_r[2] + 8.f) || (tl[3] > m_r[3] + 8.f);
    if (__any(grow)) {
#pragma unroll
      for (int r = 0; r < 4; r++) {
        float t = tl[r];
        t = fmaxf(t, __shfl_xor(t, 1));
        t = fmaxf(t, __shfl_xor(t, 2));
        t = fmaxf(t, __shfl_xor(t, 4));
        t = fmaxf(t, __shfl_xor(t, 8));
        float mnew = fmaxf(m_r[r], t);
        float al = __expf(m_r[r] - mnew);
        m_r[r] = mnew;
        l_r[r] *= al;
#pragma unroll
        for (int nb = 0; nb < 4; nb++) o_acc[nb][r] *= al;
      }
    }

    float rs[4] = {0.f, 0.f, 0.f, 0.f};
#pragma unroll
    for (int nb = 0; nb < 4; nb++) {
      float p0 = __expf(s[nb][0] - m_r[0]);
      float p1 = __expf(s[nb][1] - m_r[1]);
      float p2 = __expf(s[nb][2] - m_r[2]);
      float p3 = __expf(s[nb][3] - m_r[3]);
      rs[0] += p0; rs[1] += p1; rs[2] += p2; rs[3] += p3;
      unsigned u01, u23;
      asm("v_cvt_pk_bf16_f32 %0, %1, %2" : "=v"(u01) : "v"(p0), "v"(p1));
      asm("v_cvt_pk_bf16_f32 %0, %1, %2" : "=v"(u23) : "v"(p2), "v"(p3));
      const int colb = 2 * (nb * 16 + n);
      const int r0 = quad * 4;
      *(short*)(PbB + (r0 + 0) * 128 + (colb ^ (((r0 + 0) & 7) << 4))) = (short)(u01 & 0xffff);
      *(short*)(PbB + (r0 + 1) * 128 + (colb ^ (((r0 + 1) & 7) << 4))) = (short)(u01 >> 16);
      *(short*)(PbB + (r0 + 2) * 128 + (colb ^ (((r0 + 2) & 7) << 4))) = (short)(u23 & 0xffff);
      *(short*)(PbB + (r0 + 3) * 128 + (colb ^ (((r0 + 3) & 7) << 4))) = (short)(u23 >> 16);
    }
#pragma unroll
    for (int r = 0; r < 4; r++) {
      float t = rs[r];
      t += __shfl_xor(t, 1); t += __shfl_xor(t, 2);
      t += __shfl_xor(t, 4); t += __shfl_xor(t, 8);
      l_r[r] += t;
    }

    // ---- PV ----
#pragma unroll
    for (int c = 0; c < 2; c++) {
      const int prx = (n & 7) << 4;
      bf16x8 pf = *(bf16x8*)(PbB + n * 128 + ((64 * c + 16 * quad) ^ prx));
#pragma unroll
      for (int nb = 0; nb < 4; nb++) {
        const int row = nb * 16 + n;
        const int rx = (row & 7) << 4;
        bf16x8 vf = *(bf16x8*)(VtB + row * 128 + ((64 * c + 16 * quad) ^ rx));
        o_acc[nb] = __builtin_amdgcn_mfma_f32_16x16x32_bf16(pf, vf, o_acc[nb], 0, 0, 0);
      }
    }
  }

#pragma unroll
  for (int r = 0; r < 4; r++) l_r[r] = 1.f / l_r[r];
#pragma unroll
  for (int nb = 0; nb < 4; nb++)
#pragma unroll
    for (int r = 0; r < 4; r++) {
      int row = qb * 64 + wave * 16 + quad * 4 + r;
      o[(size_t)row * 1024 + head * 64 + nb * 16 + n] = f2bf(o_acc[nb][r] * l_r[r]);
    }
}

// ---------------------------------------------------------------------------
// x = LayerNorm(x + delta)*g + b, in place; also writes bf16 copy xb
// ---------------------------------------------------------------------------
__global__ __launch_bounds__(256)
void add_ln_kernel(float* __restrict__ x, const float* __restrict__ d,
                   const float* __restrict__ g, const float* __restrict__ b,
                   short* __restrict__ xb)
{
  __shared__ float sb[4];
  const int row = blockIdx.x, tid = threadIdx.x;
  float* xr = x + (size_t)row * 1024;
  const float* dr = d + (size_t)row * 1024;

  float v[4]; float s = 0.f, ss = 0.f;
#pragma unroll
  for (int i = 0; i < 4; i++) {
    int c = tid + 256 * i;
    v[i] = xr[c] + dr[c];
    s += v[i]; ss += v[i] * v[i];
  }
#pragma unroll
  for (int off = 32; off; off >>= 1) { s += __shfl_down(s, off); ss += __shfl_down(ss, off); }
  const int lane = tid & 63, wid = tid >> 6;
  if (lane == 0) sb[wid] = s;
  __syncthreads();
  s = sb[0] + sb[1] + sb[2] + sb[3];
  __syncthreads();
  if (lane == 0) sb[wid] = ss;
  __syncthreads();
  ss = sb[0] + sb[1] + sb[2] + sb[3];

  float mean = s * (1.f / 1024.f);
  float var  = ss * (1.f / 1024.f) - mean * mean;
  float inv  = rsqrtf(var + 1e-5f);
#pragma unroll
  for (int i = 0; i < 4; i++) {
    int c = tid + 256 * i;
    float o = (v[i] - mean) * inv * g[c] + b[c];
    xr[c] = o;
    xb[(size_t)row * 1024 + c] = f2bf(o);
  }
}

// ---------------------------------------------------------------------------
// logits + softmax/entropy (unchanged, fp32)
// ---------------------------------------------------------------------------
__global__ __launch_bounds__(256)
void logits_kernel(const float* __restrict__ h1, const float* __restrict__ w2,
                   const float* __restrict__ b2, float* __restrict__ out)
{
  const int lane = threadIdx.x & 63;
  const int row = blockIdx.x * 4 + (threadIdx.x >> 6);
  const float* hr = h1 + (size_t)row * 512;
  float s = 0.f;
#pragma unroll
  for (int i = 0; i < 8; i++) s += hr[lane + 64 * i] * w2[lane + 64 * i];
#pragma unroll
  for (int off = 32; off; off >>= 1) s += __shfl_down(s, off);
  if (lane == 0) {
    out[4097 + row] = s + b2[0];
  }
}

__global__ __launch_bounds__(1024)
void softmax_entropy_kernel(const float* __restrict__ lg, float* __restrict__ out)
{
  __shared__ float sb[16];
  const int tid = threadIdx.x;
  const int lane = tid & 63, wid = tid >> 6;

  float l0[4];
#pragma unroll
  for (int i = 0; i < 4; i++) l0[i] = lg[tid + 1024 * i];

  float mx = fmaxf(fmaxf(l0[0], l0[1]), fmaxf(l0[2], l0[3]));
#pragma unroll
  for (int off = 32; off; off >>= 1) mx = fmaxf(mx, __shfl_down(mx, off));
  if (lane == 0) sb[wid] = mx;
  __syncthreads();
  if (tid == 0) { float m = sb[0]; for (int i = 1; i < 16; i++) m = fmaxf(m, sb[i]); sb[0] = m; }
  __syncthreads();
  mx = sb[0];
  __syncthreads();

  float e[4], s = 0.f;
#pragma unroll
  for (int i = 0; i < 4; i++) { e[i] = expf(l0[i] - mx); s += e[i]; }
#pragma unroll
  for (int off = 32; off; off >>= 1) s += __shfl_down(s, off);
  if (lane == 0) sb[wid] = s;
  __syncthreads();
  if (tid == 0) { float t = 0.f; for (int i = 0; i < 16; i++) t += sb[i]; sb[0] = t; }
  __syncthreads();
  float inv = 1.f / sb[0];
  __syncthreads();

  float h = 0.f;
#pragma unroll
  for (int i = 0; i < 4; i++) {
    float p = e[i] * inv;
    out[tid + 1024 * i] = p;
    h += p * logf(p + 1e-12f);
  }
#pragma unroll
  for (int off = 32; off; off >>= 1) h += __shfl_down(h, off);
  if (lane == 0) sb[wid] = h;
  __syncthreads();
  if (tid == 0) { float t = 0.f; for (int i = 0; i < 16; i++) t += sb[i]; out[4096] = -t; }
}

// ---------------------------------------------------------------------------
extern "C" void kernel_launch(void* const* d_in, const int* in_sizes, int n_in,
                              void* d_out, int out_size, void* d_ws, size_t ws_size,
                              hipStream_t stream)
{
  const float* node_emb   = (const float*)d_in[0];
  const int*   tile_ids   = (const int*)d_in[1];
  const float* entropies  = (const float*)d_in[2];
  const int*   Ny_p       = (const int*)d_in[3];
  const float* in_w       = (const float*)d_in[4];
  const float* in_b       = (const float*)d_in[5];
  const float* attn_in_w  = (const float*)d_in[6];
  const float* attn_in_b  = (const float*)d_in[7];
  const float* attn_out_w = (const float*)d_in[8];
  const float* attn_out_b = (const float*)d_in[9];
  const float* ff_w1      = (const float*)d_in[10];
  const float* ff_b1      = (const float*)d_in[11];
  const float* ff_w2      = (const float*)d_in[12];
  const float* ff_b2      = (const float*)d_in[13];
  const float* ln1_g      = (const float*)d_in[14];
  const float* ln1_b      = (const float*)d_in[15];
  const float* ln2_g      = (const float*)d_in[16];
  const float* ln2_b      = (const float*)d_in[17];
  const float* sh_w0      = (const float*)d_in[18];
  const float* sh_b0      = (const float*)d_in[19];
  const float* sh_w1      = (const float*)d_in[20];
  const float* sh_b1      = (const float*)d_in[21];
  const float* sh_w2      = (const float*)d_in[22];
  const float* sh_b2      = (const float*)d_in[23];
  float* out = (float*)d_out;

  // Workspace (byte offsets; peak 88 MB = prior 80 MB + 8 MB bf16 weight scratch).
  char* w8 = (char*)d_ws;
  float* X    = (float*)(w8);                        // [0,16M)  fp32 x, persistent
  short* Xb   = (short*)(w8 + (16u << 20));          // [16,24M) bf16 x
  short* XRb  = (short*)(w8 + (24u << 20));          // [24,32M) bf16 rope(x); later H0b
  short* QKb  = (short*)(w8 + (32u << 20));          // [32,48M) bf16 q|k; later Hb, H1
  short* Vb   = (short*)(w8 + (48u << 20));          // [48,56M) bf16 v
  short* Ob   = (short*)(w8 + (56u << 20));          // [56,64M) bf16 attn out; also A0b
  float* O2   = (float*)(w8 + (64u << 20));          // [64,80M) fp32 out-proj / ffn-out
  short* Wb   = (short*)(w8 + (80u << 20));          // [80,88M) bf16 weight scratch (JIT)
  short* Hb   = QKb;
  short* A0b  = Ob;
  short* H0b  = XRb;
  float* H1   = (float*)(w8 + (32u << 20));

  // gather + convert node_emb rows
  gather_conv_kernel<<<UN * DN / 256, 256, 0, stream>>>(node_emb, tile_ids, A0b);

  // x = [gather, entropies] @ in_w.T + in_b  (K=1024 MFMA + rank-1 entropy col)
  convw_in_kernel<<<DN * DN / 256, 256, 0, stream>>>(in_w, Wb);
  gemm_bf16<64><<<dim3(64, 8), 256, 0, stream>>>(A0b, 1024, Wb, 1024, in_b,
      X, Xb, 1024, 1024, 0, entropies, in_w + 1024, 1025);

  for (int l = 0; l < LN_; l++) {
    const float* b_qkv = attn_in_b + (size_t)l * 3 * DN;

    convw_kernel<<<3 * DN * DN / 2048, 256, 0, stream>>>(attn_in_w + (size_t)l * 3 * DN * DN, Wb);
    rope_kernel<<<UN * DN / 256, 256, 0, stream>>>(X, XRb, tile_ids, Ny_p);
    // q|k fused (N=2048)
    gemm_bf16<128><<<dim3(32, 16), 256, 0, stream>>>(XRb, 1024, Wb, 1024, b_qkv,
        nullptr, QKb, 2048, 1024, 0, nullptr, nullptr, 0);
    // v
    gemm_bf16<64><<<dim3(64, 8), 256, 0, stream>>>(Xb, 1024, Wb + (size_t)2048 * 1024, 1024,
        b_qkv + 2048, nullptr, Vb, 1024, 1024, 0, nullptr, nullptr, 0);
    attn_mfma_kernel<<<dim3(UN / 64, HN), 256, 0, stream>>>(QKb, Vb, Ob);
    convw_kernel<<<DN * DN / 2048, 256, 0, stream>>>(attn_out_w + (size_t)l * DN * DN, Wb);
    gemm_bf16<64><<<dim3(64, 8), 256, 0, stream>>>(Ob, 1024, Wb, 1024,
        attn_out_b + (size_t)l * DN, O2, nullptr, 1024, 1024, 0, nullptr, nullptr, 0);
    add_ln_kernel<<<UN, 256, 0, stream>>>(X, O2, ln1_g + (size_t)l * DN, ln1_b + (size_t)l * DN, Xb);
    convw_kernel<<<2 * DN * DN / 2048, 256, 0, stream>>>(ff_w1 + (size_t)l * 2 * DN * DN, Wb);
    gemm_bf16<128><<<dim3(32, 16), 256, 0, stream>>>(Xb, 1024, Wb, 1024,
        ff_b1 + (size_t)l * 2 * DN, nullptr, Hb, 2048, 1024, 1, nullptr, nullptr, 0);
    convw_kernel<<<2 * DN * DN / 2048, 256, 0, stream>>>(ff_w2 + (size_t)l * DN * 2 * DN, Wb);
    gemm_bf16<64><<<dim3(64, 8), 256, 0, stream>>>(Hb, 2048, Wb, 2048,
        ff_b2 + (size_t)l * DN, O2, nullptr, 1024, 2048, 0, nullptr, nullptr, 0);
    add_ln_kernel<<<UN, 256, 0, stream>>>(X, O2, ln2_g + (size_t)l * DN, ln2_b + (size_t)l * DN, Xb);
  }

  // head MLP
  convw_kernel<<<512 * DN / 2048, 256, 0, stream>>>(sh_w0, Wb);
  gemm_bf16<64><<<dim3(64, 4), 256, 0, stream>>>(Xb, 1024, Wb, 1024, sh_b0,
      nullptr, H0b, 512, 1024, 1, nullptr, nullptr, 0);
  convw_kernel<<<512 * 512 / 2048, 256, 0, stream>>>(sh_w1, Wb);
  gemm_bf16<64><<<dim3(64, 4), 256, 0, stream>>>(H0b, 512, Wb, 512, sh_b1,
      H1, nullptr, 512, 512, 1, nullptr, nullptr, 0);
  logits_kernel<<<UN / 4, 256, 0, stream>>>(H1, sh_w2, sh_b2, out);
  softmax_entropy_kernel<<<1, 1024, 0, stream>>>(out + 4097, out);
}

// Round 2
// 1968.438 us; speedup vs baseline: 1.4343x; 1.0410x over previous
//
#include <hip/hip_runtime.h>
#include <hip/hip_bf16.h>
#include <math.h>

// Problem constants
#define UN 4096      // units
#define DN 1024      // model dim
#define LN_ 4        // layers
#define HN 16        // heads
#define HD 64        // head dim

typedef __attribute__((ext_vector_type(8))) short bf16x8;   // 8 bf16 = 4 VGPRs
typedef __attribute__((ext_vector_type(4))) float f32x4;

#define LGKM0 asm volatile("s_waitcnt lgkmcnt(0)" ::: "memory")
#define BARRIER0 __builtin_amdgcn_s_barrier()
#define SCHED0 __builtin_amdgcn_sched_barrier(0)

// float -> bf16 bits, round-to-nearest-even
__device__ __forceinline__ short f2bf(float f) {
  union { float f; unsigned u; } x; x.f = f;
  unsigned r = x.u + 0x7fffu + ((x.u >> 16) & 1u);
  return (short)(r >> 16);
}
__device__ __forceinline__ float bf2f(short b) {
  union { unsigned u; float f; } x; x.u = ((unsigned)(unsigned short)b) << 16;
  return x.f;
}

// async global->LDS, 16B per lane. LDS dest = wave-uniform base + lane*16.
__device__ __forceinline__ void gload16(const void* g, void* l) {
  __builtin_amdgcn_global_load_lds(
      (const __attribute__((address_space(1))) void*)g,
      (__attribute__((address_space(3))) void*)l, 16, 0, 0);
}

// ---------------------------------------------------------------------------
// fp32 -> bf16 weight conversion (contiguous), 8 elts/thread
// ---------------------------------------------------------------------------
__global__ __launch_bounds__(256)
void convw_kernel(const float* __restrict__ src, short* __restrict__ dst)
{
  int i = blockIdx.x * 256 + threadIdx.x;           // handles elements [8i, 8i+8)
  float4 f0 = ((const float4*)src)[i * 2];
  float4 f1 = ((const float4*)src)[i * 2 + 1];
  bf16x8 o;
  o[0] = f2bf(f0.x); o[1] = f2bf(f0.y); o[2] = f2bf(f0.z); o[3] = f2bf(f0.w);
  o[4] = f2bf(f1.x); o[5] = f2bf(f1.y); o[6] = f2bf(f1.z); o[7] = f2bf(f1.w);
  ((bf16x8*)dst)[i] = o;
}

// in_w is [1024][1025]; repack first 1024 cols to bf16 [1024][1024]
__global__ __launch_bounds__(256)
void convw_in_kernel(const float* __restrict__ src, short* __restrict__ dst)
{
  int idx = blockIdx.x * 256 + threadIdx.x;         // < 1024*1024
  int r = idx >> 10, c = idx & 1023;
  dst[idx] = f2bf(src[r * 1025 + c]);
}

// ---------------------------------------------------------------------------
// bf16 MFMA GEMM, 2-phase double-buffered (T3-lite + counted vmcnt T4):
// C[m][n] = act( sum_k A[m][k]*W[n][k] + bias[n] [+ ent[m]*wcol[n]] )
// A: M x K bf16 (lda). W: N x K bf16 (ldw) — pre-converted.
// Staging via global_load_lds width=16 into LINEAR LDS, next tile's loads
// issued before compute; s_waitcnt vmcnt(LOADS) keeps them in flight.
// TM=128: tile 128x128, 4 waves 2x2 of 64x64, acc 4x4.
// TM=64 : tile  64x128, 4 waves 2x2 of 32x64, acc 2x4  (2x grid for N<=1024).
// M%TM==0, N%128==0, K%32==0, lda/ldw multiples of 8 (16B rows).
// ---------------------------------------------------------------------------
template<int TM>
__global__ __launch_bounds__(256)
void gemm_bf16(const short* __restrict__ A, int lda,
               const short* __restrict__ W, int ldw,
               const float* __restrict__ bias,
               float* __restrict__ C32, short* __restrict__ C16, int ldc,
               int K, int relu,
               const float* __restrict__ ent, const float* __restrict__ wcol,
               int wstride)
{
  constexpr int MBF = TM / 32;      // M-frags per wave: 4 or 2
  constexpr int AIN = TM / 64;      // A gload insts per wave: 2 or 1
  constexpr int NLD = AIN + 2;      // gloads per wave per tile
  __shared__ __align__(16) short As[2][TM][32];
  __shared__ __align__(16) short Ws[2][128][32];

  const int tid  = threadIdx.x;
  const int bm = blockIdx.x, bn = blockIdx.y;
  const int lane = tid & 63, wave = tid >> 6;
  const int n = lane & 15, quad = lane >> 4;
  const int mw = (wave >> 1) * (TM / 2), nw = (wave & 1) * 64;

  f32x4 acc[MBF][4];
#pragma unroll
  for (int mb = 0; mb < MBF; mb++)
#pragma unroll
    for (int nb = 0; nb < 4; nb++)
#pragma unroll
      for (int r = 0; r < 4; r++) acc[mb][nb][r] = 0.f;

  // staging map: per gload inst a wave writes 1024B = 16 rows x 64B.
  const int sr = lane >> 2;
  const int sc = (lane & 3) * 8;
  const short* aSrc[AIN];
#pragma unroll
  for (int i = 0; i < AIN; i++)
    aSrc[i] = A + (size_t)(bm * TM + wave * (16 * AIN) + i * 16 + sr) * lda + sc;
  const short* wSrc[2];
#pragma unroll
  for (int i = 0; i < 2; i++)
    wSrc[i] = W + (size_t)(bn * 128 + wave * 32 + i * 16 + sr) * ldw + sc;

  auto stage = [&](int buf, int kk) {
#pragma unroll
    for (int i = 0; i < AIN; i++)
      gload16(aSrc[i] + kk, &As[buf][wave * (16 * AIN) + i * 16][0]);
#pragma unroll
    for (int i = 0; i < 2; i++)
      gload16(wSrc[i] + kk, &Ws[buf][wave * 32 + i * 16][0]);
  };

  stage(0, 0);
  int cur = 0;
  for (int kk = 0; kk < K; kk += 32) {
    if (kk + 32 < K) {
      stage(cur ^ 1, kk + 32);
      asm volatile("s_waitcnt vmcnt(%0)" :: "n"(NLD) : "memory");
    } else {
      asm volatile("s_waitcnt vmcnt(0)" ::: "memory");
    }
    BARRIER0; SCHED0;            // buf[cur] ready for all waves

    bf16x8 af[MBF], bfr[4];
#pragma unroll
    for (int mb = 0; mb < MBF; mb++) af[mb] = *(bf16x8*)&As[cur][mw + mb * 16 + n][quad * 8];
#pragma unroll
    for (int nb = 0; nb < 4; nb++)   bfr[nb] = *(bf16x8*)&Ws[cur][nw + nb * 16 + n][quad * 8];
#pragma unroll
    for (int mb = 0; mb < MBF; mb++)
#pragma unroll
      for (int nb = 0; nb < 4; nb++)
        acc[mb][nb] = __builtin_amdgcn_mfma_f32_16x16x32_bf16(af[mb], bfr[nb], acc[mb][nb], 0, 0, 0);

    LGKM0; BARRIER0; SCHED0;     // all waves done reading buf[cur]
    cur ^= 1;
  }

  // ---- epilogue (MFMA C-layout: row = quad*4+r, col = n within 16x16) ----
#pragma unroll
  for (int mb = 0; mb < MBF; mb++) {
    float entv[4];
#pragma unroll
    for (int r = 0; r < 4; r++)
      entv[r] = ent ? ent[bm * TM + mw + mb * 16 + quad * 4 + r] : 0.f;
#pragma unroll
    for (int nb = 0; nb < 4; nb++) {
      const int col = bn * 128 + nw + nb * 16 + n;
      const float bs = bias[col];
      const float wc = ent ? wcol[(size_t)col * wstride] : 0.f;
#pragma unroll
      for (int r = 0; r < 4; r++) {
        const int row = bm * TM + mw + mb * 16 + quad * 4 + r;
        float v = acc[mb][nb][r] + bs;
        if (ent)  v += entv[r] * wc;
        if (relu) v = fmaxf(v, 0.f);
        if (C32) C32[(size_t)row * ldc + col] = v;
        if (C16) C16[(size_t)row * ldc + col] = f2bf(v);
      }
    }
  }
}

// ---------------------------------------------------------------------------
// gather + fp32->bf16: dst[u][k] = bf16(node_emb[ids[u]][k])
// ---------------------------------------------------------------------------
__global__ __launch_bounds__(256)
void gather_conv_kernel(const float* __restrict__ emb, const int* __restrict__ ids,
                        short* __restrict__ dst)
{
  int idx = blockIdx.x * 256 + threadIdx.x;   // < UN*DN
  int u = idx >> 10;
  dst[idx] = f2bf(emb[(size_t)ids[u] * 1024 + (idx & 1023)]);
}

// ---------------------------------------------------------------------------
// RoPE: reads X fp32, writes bf16 xr
// ---------------------------------------------------------------------------
__global__ __launch_bounds__(256)
void rope_kernel(const float* __restrict__ x, short* __restrict__ xr,
                 const int* __restrict__ ids, const int* __restrict__ nyp)
{
  int idx = blockIdx.x * 256 + threadIdx.x;
  int u = idx >> 10, j = idx & 1023;
  int blk = j >> 9, o = j & 511;
  int i = o & 255;
  int t = ids[u];
  int ny = *nyp;
  float pos = (blk == 0) ? (float)(t / ny) : (float)(t % ny);
  float theta = expf((float)i * -0.0359778921f);   // -ln(10000)/256
  float ang = pos * theta;
  float c = cosf(ang), sn = sinf(ang);
  const float* xrow = x + (size_t)u * 1024 + blk * 512;
  float x1 = xrow[i];
  float x2 = xrow[256 + i];
  xr[idx] = f2bf((o < 256) ? (x1 * c - x2 * sn) : (x1 * sn + x2 * c));
}

// ---------------------------------------------------------------------------
// MFMA bf16 flash attention, T14 pipelined (reg-staged K/V, issue-early /
// write-late), raw barriers + lgkmcnt only (prefetch stays in flight).
// qk: bf16 [4096][2048] fused q|k; v: bf16 [4096][1024]; o: bf16 [4096][1024].
// LDS rows 128 B XOR-swizzled (byte ^= (row&7)<<4) — conflict-free (round 1).
// Deferred-max (THR=8) + deferred l-sum (per-lane partial, one butterfly at
// end). setprio(1) around MFMA clusters (T5). XCD chunk swizzle of (qb,head).
// ---------------------------------------------------------------------------
__global__ __launch_bounds__(256)
void attn_mfma_kernel(const short* __restrict__ qk, const short* __restrict__ v,
                      short* __restrict__ o)
{
  __shared__ __align__(16) short Kt[64][64];        // [key][d]  swizzled
  __shared__ __align__(16) short Vt[64][64];        // [d][key]  swizzled
  __shared__ __align__(16) short Pb[4][16][64];     // per-wave P slab, swizzled

  const int tid  = threadIdx.x;
  const int lane = tid & 63;
  const int wave = tid >> 6;

  // XCD chunk swizzle: 1024 blocks, 8 XCDs -> each XCD gets 2 whole heads.
  int wg = blockIdx.x + 64 * blockIdx.y;
  wg = (wg & 7) * 128 + (wg >> 3);
  const int qb   = wg & 63;
  const int head = wg >> 6;

  const int n    = lane & 15;
  const int quad = lane >> 4;

  // Q fragments: row = qb*64 + wave*16 + n ; scale 1/8 exact (pow2)
  bf16x8 qfrag[2];
  {
    const int qrow = qb * 64 + wave * 16 + n;
    const short* qptr = qk + (size_t)qrow * 2048 + head * 64 + quad * 8;
#pragma unroll
    for (int c = 0; c < 2; c++)
#pragma unroll
      for (int j = 0; j < 8; j++)
        qfrag[c][j] = f2bf(bf2f(qptr[c * 32 + j]) * 0.125f);
  }

  float m_r[4], l_r[4];                 // l_r = PER-LANE partial sum (deferred)
  f32x4 o_acc[4];
#pragma unroll
  for (int r = 0; r < 4; r++) { m_r[r] = -3.0e38f; l_r[r] = 0.f; }
#pragma unroll
  for (int nb = 0; nb < 4; nb++)
#pragma unroll
    for (int r = 0; r < 4; r++) o_acc[nb][r] = 0.f;

  const int skey = tid & 63;          // staging: key row
  const int sd0  = wave * 16;         // staging: d-chunk
  const int krx  = (skey & 7) << 4;   // Kt store swizzle for this thread

  char* KtB = (char*)&Kt[0][0];
  char* VtB = (char*)&Vt[0][0];
  char* PbB = (char*)&Pb[wave][0][0];

  auto loadT = [&](int kt, bf16x8& k0, bf16x8& k1, bf16x8& v0, bf16x8& v1) {
    const short* kp = qk + (size_t)(kt * 64 + skey) * 2048 + 1024 + head * 64 + sd0;
    k0 = *(const bf16x8*)(kp);
    k1 = *(const bf16x8*)(kp + 8);
    const short* vp = v + (size_t)(kt * 64 + skey) * 1024 + head * 64 + sd0;
    v0 = *(const bf16x8*)(vp);
    v1 = *(const bf16x8*)(vp + 8);
  };

  auto writeT = [&](bf16x8 k0, bf16x8 k1, bf16x8 v0, bf16x8 v1) {
    *(bf16x8*)(KtB + skey * 128 + ((sd0 * 2)      ^ krx)) = k0;
    *(bf16x8*)(KtB + skey * 128 + ((sd0 * 2 + 16) ^ krx)) = k1;
#pragma unroll
    for (int i = 0; i < 8; i++) {
      int d = sd0 + i;
      *(short*)(VtB + d * 128 + ((2 * skey) ^ ((d & 7) << 4))) = v0[i];
    }
#pragma unroll
    for (int i = 0; i < 8; i++) {
      int d = sd0 + 8 + i;
      *(short*)(VtB + d * 128 + ((2 * skey) ^ ((d & 7) << 4))) = v1[i];
    }
  };

  auto computeT = [&]() {
    // ---- QK^T ----
    f32x4 s[4];
#pragma unroll
    for (int nb = 0; nb < 4; nb++) {
      const int row = nb * 16 + n;
      const int rx = (n & 7) << 4;
      bf16x8 k0 = *(bf16x8*)(KtB + row * 128 + ((quad * 16)      ^ rx));
      bf16x8 k1 = *(bf16x8*)(KtB + row * 128 + ((64 + quad * 16) ^ rx));
      f32x4 z = {0.f, 0.f, 0.f, 0.f};
      __builtin_amdgcn_s_setprio(1);
      z = __builtin_amdgcn_mfma_f32_16x16x32_bf16(qfrag[0], k0, z, 0, 0, 0);
      z = __builtin_amdgcn_mfma_f32_16x16x32_bf16(qfrag[1], k1, z, 0, 0, 0);
      __builtin_amdgcn_s_setprio(0);
      s[nb] = z;
    }

    // ---- online softmax, deferred max (THR=8), deferred l-sum ----
    float tl[4];
#pragma unroll
    for (int r = 0; r < 4; r++)
      tl[r] = fmaxf(fmaxf(s[0][r], s[1][r]), fmaxf(s[2][r], s[3][r]));
    bool grow = (tl[0] > m_r[0] + 8.f) || (tl[1] > m_r[1] + 8.f) ||
                (tl[2] > m_r[2] + 8.f) || (tl[3] > m_r[3] + 8.f);
    if (__any(grow)) {
#pragma unroll
      for (int r = 0; r < 4; r++) {
        float t = tl[r];
        t = fmaxf(t, __shfl_xor(t, 1));
        t = fmaxf(t, __shfl_xor(t, 2));
        t = fmaxf(t, __shfl_xor(t, 4));
        t = fmaxf(t, __shfl_xor(t, 8));
        float mnew = fmaxf(m_r[r], t);
        float al = __expf(m_r[r] - mnew);
        m_r[r] = mnew;
        l_r[r] *= al;
#pragma unroll
        for (int nb = 0; nb < 4; nb++) o_acc[nb][r] *= al;
      }
    }

#pragma unroll
    for (int nb = 0; nb < 4; nb++) {
      float p0 = __expf(s[nb][0] - m_r[0]);
      float p1 = __expf(s[nb][1] - m_r[1]);
      float p2 = __expf(s[nb][2] - m_r[2]);
      float p3 = __expf(s[nb][3] - m_r[3]);
      l_r[0] += p0; l_r[1] += p1; l_r[2] += p2; l_r[3] += p3;
      unsigned u01, u23;
      asm("v_cvt_pk_bf16_f32 %0, %1, %2" : "=v"(u01) : "v"(p0), "v"(p1));
      asm("v_cvt_pk_bf16_f32 %0, %1, %2" : "=v"(u23) : "v"(p2), "v"(p3));
      const int colb = 2 * (nb * 16 + n);
      const int r0 = quad * 4;
      *(short*)(PbB + (r0 + 0) * 128 + (colb ^ (((r0 + 0) & 7) << 4))) = (short)(u01 & 0xffff);
      *(short*)(PbB + (r0 + 1) * 128 + (colb ^ (((r0 + 1) & 7) << 4))) = (short)(u01 >> 16);
      *(short*)(PbB + (r0 + 2) * 128 + (colb ^ (((r0 + 2) & 7) << 4))) = (short)(u23 & 0xffff);
      *(short*)(PbB + (r0 + 3) * 128 + (colb ^ (((r0 + 3) & 7) << 4))) = (short)(u23 >> 16);
    }

    // ---- PV ----
#pragma unroll
    for (int c = 0; c < 2; c++) {
      const int prx = (n & 7) << 4;
      bf16x8 pf = *(bf16x8*)(PbB + n * 128 + ((64 * c + 16 * quad) ^ prx));
#pragma unroll
      for (int nb = 0; nb < 4; nb++) {
        const int row = nb * 16 + n;
        const int rx = (n & 7) << 4;
        bf16x8 vf = *(bf16x8*)(VtB + row * 128 + ((64 * c + 16 * quad) ^ rx));
        __builtin_amdgcn_s_setprio(1);
        o_acc[nb] = __builtin_amdgcn_mfma_f32_16x16x32_bf16(pf, vf, o_acc[nb], 0, 0, 0);
        __builtin_amdgcn_s_setprio(0);
      }
    }
  };

  // ---- T14 pipelined main loop (unroll x2 for static dual regsets) ----
  bf16x8 ka0, ka1, va0, va1, kb0, kb1, vb0, vb1;
  loadT(0, ka0, ka1, va0, va1);
  for (int kt = 0; kt < 64; kt += 2) {
    LGKM0; BARRIER0; SCHED0;          // all waves done reading prev tile
    writeT(ka0, ka1, va0, va1);       // vmcnt waits on A-regs inserted here
    loadT(kt + 1, kb0, kb1, vb0, vb1);
    LGKM0; BARRIER0; SCHED0;          // tile kt visible in LDS
    computeT();

    LGKM0; BARRIER0; SCHED0;
    writeT(kb0, kb1, vb0, vb1);
    if (kt + 2 < 64) loadT(kt + 2, ka0, ka1, va0, va1);
    LGKM0; BARRIER0; SCHED0;
    computeT();
  }

  // final l reduction (deferred) + output
#pragma unroll
  for (int r = 0; r < 4; r++) {
    float t = l_r[r];
    t += __shfl_xor(t, 1); t += __shfl_xor(t, 2);
    t += __shfl_xor(t, 4); t += __shfl_xor(t, 8);
    l_r[r] = 1.f / t;
  }
#pragma unroll
  for (int nb = 0; nb < 4; nb++)
#pragma unroll
    for (int r = 0; r < 4; r++) {
      int row = qb * 64 + wave * 16 + quad * 4 + r;
      o[(size_t)row * 1024 + head * 64 + nb * 16 + n] = f2bf(o_acc[nb][r] * l_r[r]);
    }
}

// ---------------------------------------------------------------------------
// x = LayerNorm(x + delta)*g + b, in place; also writes bf16 copy xb
// ---------------------------------------------------------------------------
__global__ __launch_bounds__(256)
void add_ln_kernel(float* __restrict__ x, const float* __restrict__ d,
                   const float* __restrict__ g, const float* __restrict__ b,
                   short* __restrict__ xb)
{
  __shared__ float sb[4];
  const int row = blockIdx.x, tid = threadIdx.x;
  float* xr = x + (size_t)row * 1024;
  const float* dr = d + (size_t)row * 1024;

  float v[4]; float s = 0.f, ss = 0.f;
#pragma unroll
  for (int i = 0; i < 4; i++) {
    int c = tid + 256 * i;
    v[i] = xr[c] + dr[c];
    s += v[i]; ss += v[i] * v[i];
  }
#pragma unroll
  for (int off = 32; off; off >>= 1) { s += __shfl_down(s, off); ss += __shfl_down(ss, off); }
  const int lane = tid & 63, wid = tid >> 6;
  if (lane == 0) sb[wid] = s;
  __syncthreads();
  s = sb[0] + sb[1] + sb[2] + sb[3];
  __syncthreads();
  if (lane == 0) sb[wid] = ss;
  __syncthreads();
  ss = sb[0] + sb[1] + sb[2] + sb[3];

  float mean = s * (1.f / 1024.f);
  float var  = ss * (1.f / 1024.f) - mean * mean;
  float inv  = rsqrtf(var + 1e-5f);
#pragma unroll
  for (int i = 0; i < 4; i++) {
    int c = tid + 256 * i;
    float o = (v[i] - mean) * inv * g[c] + b[c];
    xr[c] = o;
    xb[(size_t)row * 1024 + c] = f2bf(o);
  }
}

// ---------------------------------------------------------------------------
// logits + softmax/entropy (unchanged, fp32)
// ---------------------------------------------------------------------------
__global__ __launch_bounds__(256)
void logits_kernel(const float* __restrict__ h1, const float* __restrict__ w2,
                   const float* __restrict__ b2, float* __restrict__ out)
{
  const int lane = threadIdx.x & 63;
  const int row = blockIdx.x * 4 + (threadIdx.x >> 6);
  const float* hr = h1 + (size_t)row * 512;
  float s = 0.f;
#pragma unroll
  for (int i = 0; i < 8; i++) s += hr[lane + 64 * i] * w2[lane + 64 * i];
#pragma unroll
  for (int off = 32; off; off >>= 1) s += __shfl_down(s, off);
  if (lane == 0) {
    out[4097 + row] = s + b2[0];
  }
}

__global__ __launch_bounds__(1024)
void softmax_entropy_kernel(const float* __restrict__ lg, float* __restrict__ out)
{
  __shared__ float sb[16];
  const int tid = threadIdx.x;
  const int lane = tid & 63, wid = tid >> 6;

  float l0[4];
#pragma unroll
  for (int i = 0; i < 4; i++) l0[i] = lg[tid + 1024 * i];

  float mx = fmaxf(fmaxf(l0[0], l0[1]), fmaxf(l0[2], l0[3]));
#pragma unroll
  for (int off = 32; off; off >>= 1) mx = fmaxf(mx, __shfl_down(mx, off));
  if (lane == 0) sb[wid] = mx;
  __syncthreads();
  if (tid == 0) { float m = sb[0]; for (int i = 1; i < 16; i++) m = fmaxf(m, sb[i]); sb[0] = m; }
  __syncthreads();
  mx = sb[0];
  __syncthreads();

  float e[4], s = 0.f;
#pragma unroll
  for (int i = 0; i < 4; i++) { e[i] = expf(l0[i] - mx); s += e[i]; }
#pragma unroll
  for (int off = 32; off; off >>= 1) s += __shfl_down(s, off);
  if (lane == 0) sb[wid] = s;
  __syncthreads();
  if (tid == 0) { float t = 0.f; for (int i = 0; i < 16; i++) t += sb[i]; sb[0] = t; }
  __syncthreads();
  float inv = 1.f / sb[0];
  __syncthreads();

  float h = 0.f;
#pragma unroll
  for (int i = 0; i < 4; i++) {
    float p = e[i] * inv;
    out[tid + 1024 * i] = p;
    h += p * logf(p + 1e-12f);
  }
#pragma unroll
  for (int off = 32; off; off >>= 1) h += __shfl_down(h, off);
  if (lane == 0) sb[wid] = h;
  __syncthreads();
  if (tid == 0) { float t = 0.f; for (int i = 0; i < 16; i++) t += sb[i]; out[4096] = -t; }
}

// ---------------------------------------------------------------------------
extern "C" void kernel_launch(void* const* d_in, const int* in_sizes, int n_in,
                              void* d_out, int out_size, void* d_ws, size_t ws_size,
                              hipStream_t stream)
{
  const float* node_emb   = (const float*)d_in[0];
  const int*   tile_ids   = (const int*)d_in[1];
  const float* entropies  = (const float*)d_in[2];
  const int*   Ny_p       = (const int*)d_in[3];
  const float* in_w       = (const float*)d_in[4];
  const float* in_b       = (const float*)d_in[5];
  const float* attn_in_w  = (const float*)d_in[6];
  const float* attn_in_b  = (const float*)d_in[7];
  const float* attn_out_w = (const float*)d_in[8];
  const float* attn_out_b = (const float*)d_in[9];
  const float* ff_w1      = (const float*)d_in[10];
  const float* ff_b1      = (const float*)d_in[11];
  const float* ff_w2      = (const float*)d_in[12];
  const float* ff_b2      = (const float*)d_in[13];
  const float* ln1_g      = (const float*)d_in[14];
  const float* ln1_b      = (const float*)d_in[15];
  const float* ln2_g      = (const float*)d_in[16];
  const float* ln2_b      = (const float*)d_in[17];
  const float* sh_w0      = (const float*)d_in[18];
  const float* sh_b0      = (const float*)d_in[19];
  const float* sh_w1      = (const float*)d_in[20];
  const float* sh_b1      = (const float*)d_in[21];
  const float* sh_w2      = (const float*)d_in[22];
  const float* sh_b2      = (const float*)d_in[23];
  float* out = (float*)d_out;

  // Workspace (byte offsets; peak 88 MB).
  char* w8 = (char*)d_ws;
  float* X    = (float*)(w8);                        // [0,16M)  fp32 x, persistent
  short* Xb   = (short*)(w8 + (16u << 20));          // [16,24M) bf16 x
  short* XRb  = (short*)(w8 + (24u << 20));          // [24,32M) bf16 rope(x); later H0b
  short* QKb  = (short*)(w8 + (32u << 20));          // [32,48M) bf16 q|k; later Hb, H1
  short* Vb   = (short*)(w8 + (48u << 20));          // [48,56M) bf16 v
  short* Ob   = (short*)(w8 + (56u << 20));          // [56,64M) bf16 attn out; also A0b
  float* O2   = (float*)(w8 + (64u << 20));          // [64,80M) fp32 out-proj / ffn-out
  short* Wb   = (short*)(w8 + (80u << 20));          // [80,88M) bf16 weight scratch (JIT)
  short* Hb   = QKb;
  short* A0b  = Ob;
  short* H0b  = XRb;
  float* H1   = (float*)(w8 + (32u << 20));

  // gather + convert node_emb rows
  gather_conv_kernel<<<UN * DN / 256, 256, 0, stream>>>(node_emb, tile_ids, A0b);

  // x = [gather, entropies] @ in_w.T + in_b  (K=1024 MFMA + rank-1 entropy col)
  convw_in_kernel<<<DN * DN / 256, 256, 0, stream>>>(in_w, Wb);
  gemm_bf16<64><<<dim3(64, 8), 256, 0, stream>>>(A0b, 1024, Wb, 1024, in_b,
      X, Xb, 1024, 1024, 0, entropies, in_w + 1024, 1025);

  for (int l = 0; l < LN_; l++) {
    const float* b_qkv = attn_in_b + (size_t)l * 3 * DN;

    convw_kernel<<<3 * DN * DN / 2048, 256, 0, stream>>>(attn_in_w + (size_t)l * 3 * DN * DN, Wb);
    rope_kernel<<<UN * DN / 256, 256, 0, stream>>>(X, XRb, tile_ids, Ny_p);
    // q|k fused (N=2048)
    gemm_bf16<128><<<dim3(32, 16), 256, 0, stream>>>(XRb, 1024, Wb, 1024, b_qkv,
        nullptr, QKb, 2048, 1024, 0, nullptr, nullptr, 0);
    // v
    gemm_bf16<64><<<dim3(64, 8), 256, 0, stream>>>(Xb, 1024, Wb + (size_t)2048 * 1024, 1024,
        b_qkv + 2048, nullptr, Vb, 1024, 1024, 0, nullptr, nullptr, 0);
    attn_mfma_kernel<<<dim3(UN / 64, HN), 256, 0, stream>>>(QKb, Vb, Ob);
    convw_kernel<<<DN * DN / 2048, 256, 0, stream>>>(attn_out_w + (size_t)l * DN * DN, Wb);
    gemm_bf16<64><<<dim3(64, 8), 256, 0, stream>>>(Ob, 1024, Wb, 1024,
        attn_out_b + (size_t)l * DN, O2, nullptr, 1024, 1024, 0, nullptr, nullptr, 0);
    add_ln_kernel<<<UN, 256, 0, stream>>>(X, O2, ln1_g + (size_t)l * DN, ln1_b + (size_t)l * DN, Xb);
    convw_kernel<<<2 * DN * DN / 2048, 256, 0, stream>>>(ff_w1 + (size_t)l * 2 * DN * DN, Wb);
    gemm_bf16<128><<<dim3(32, 16), 256, 0, stream>>>(Xb, 1024, Wb, 1024,
        ff_b1 + (size_t)l * 2 * DN, nullptr, Hb, 2048, 1024, 1, nullptr, nullptr, 0);
    convw_kernel<<<2 * DN * DN / 2048, 256, 0, stream>>>(ff_w2 + (size_t)l * DN * 2 * DN, Wb);
    gemm_bf16<64><<<dim3(64, 8), 256, 0, stream>>>(Hb, 2048, Wb, 2048,
        ff_b2 + (size_t)l * DN, O2, nullptr, 1024, 2048, 0, nullptr, nullptr, 0);
    add_ln_kernel<<<UN, 256, 0, stream>>>(X, O2, ln2_g + (size_t)l * DN, ln2_b + (size_t)l * DN, Xb);
  }

  // head MLP
  convw_kernel<<<512 * DN / 2048, 256, 0, stream>>>(sh_w0, Wb);
  gemm_bf16<64><<<dim3(64, 4), 256, 0, stream>>>(Xb, 1024, Wb, 1024, sh_b0,
      nullptr, H0b, 512, 1024, 1, nullptr, nullptr, 0);
  convw_kernel<<<512 * 512 / 2048, 256, 0, stream>>>(sh_w1, Wb);
  gemm_bf16<64><<<dim3(64, 4), 256, 0, stream>>>(H0b, 512, Wb, 512, sh_b1,
      H1, nullptr, 512, 512, 1, nullptr, nullptr, 0);
  logits_kernel<<<UN / 4, 256, 0, stream>>>(H1, sh_w2, sh_b2, out);
  softmax_entropy_kernel<<<1, 1024, 0, stream>>>(out + 4097, out);
}

// Round 4
// 1798.453 us; speedup vs baseline: 1.5699x; 1.0945x over previous
//
#include <hip/hip_runtime.h>
#include <hip/hip_bf16.h>
#include <math.h>

// Problem constants
#define UN 4096      // units
#define DN 1024      // model dim
#define LN_ 4        // layers
#define HN 16        // heads
#define HD 64        // head dim

typedef __attribute__((ext_vector_type(8))) short bf16x8;   // 8 bf16 = 4 VGPRs
typedef __attribute__((ext_vector_type(4))) float f32x4;

#define LGKM0 asm volatile("s_waitcnt lgkmcnt(0)" ::: "memory")
#define BARRIER0 __builtin_amdgcn_s_barrier()
#define SCHED0 __builtin_amdgcn_sched_barrier(0)

// float -> bf16 bits, round-to-nearest-even
__device__ __forceinline__ short f2bf(float f) {
  union { float f; unsigned u; } x; x.f = f;
  unsigned r = x.u + 0x7fffu + ((x.u >> 16) & 1u);
  return (short)(r >> 16);
}
__device__ __forceinline__ float bf2f(short b) {
  union { unsigned u; float f; } x; x.u = ((unsigned)(unsigned short)b) << 16;
  return x.f;
}

// async global->LDS, 16B per lane. LDS dest = wave-uniform base + lane*16.
__device__ __forceinline__ void gload16(const void* g, void* l) {
  __builtin_amdgcn_global_load_lds(
      (const __attribute__((address_space(1))) void*)g,
      (__attribute__((address_space(3))) void*)l, 16, 0, 0);
}

// ---------------------------------------------------------------------------
// fp32 -> bf16 weight conversion (contiguous), 8 elts/thread
// ---------------------------------------------------------------------------
__global__ __launch_bounds__(256)
void convw_kernel(const float* __restrict__ src, short* __restrict__ dst)
{
  int i = blockIdx.x * 256 + threadIdx.x;           // handles elements [8i, 8i+8)
  float4 f0 = ((const float4*)src)[i * 2];
  float4 f1 = ((const float4*)src)[i * 2 + 1];
  bf16x8 o;
  o[0] = f2bf(f0.x); o[1] = f2bf(f0.y); o[2] = f2bf(f0.z); o[3] = f2bf(f0.w);
  o[4] = f2bf(f1.x); o[5] = f2bf(f1.y); o[6] = f2bf(f1.z); o[7] = f2bf(f1.w);
  ((bf16x8*)dst)[i] = o;
}

// in_w is [1024][1025]; repack first 1024 cols to bf16 [1024][1024]
__global__ __launch_bounds__(256)
void convw_in_kernel(const float* __restrict__ src, short* __restrict__ dst)
{
  int idx = blockIdx.x * 256 + threadIdx.x;         // < 1024*1024
  int r = idx >> 10, c = idx & 1023;
  dst[idx] = f2bf(src[r * 1025 + c]);
}

// ---------------------------------------------------------------------------
// bf16 MFMA GEMM, 2-phase double-buffered (counted vmcnt) — r2-verified:
// C[m][n] = act( sum_k A[m][k]*W[n][k] + bias[n] + rbias[m] [+ ent[m]*wcol[n]] )
// A: M x K bf16 (lda). W: N x K bf16 (ldw) — pre-converted.
// TM=128: tile 128x128, 4 waves 2x2 of 64x64, acc 4x4.
// TM=64 : tile  64x128, 4 waves 2x2 of 32x64, acc 2x4.
// M%TM==0, N%128==0, K%32==0, lda/ldw multiples of 8 (16B rows).
// ---------------------------------------------------------------------------
template<int TM>
__global__ __launch_bounds__(256)
void gemm_bf16(const short* __restrict__ A, int lda,
               const short* __restrict__ W, int ldw,
               const float* __restrict__ bias,
               float* __restrict__ C32, short* __restrict__ C16, int ldc,
               int K, int relu,
               const float* __restrict__ ent, const float* __restrict__ wcol,
               int wstride, const float* __restrict__ rbias)
{
  constexpr int MBF = TM / 32;      // M-frags per wave: 4 or 2
  constexpr int AIN = TM / 64;      // A gload insts per wave: 2 or 1
  constexpr int NLD = AIN + 2;      // gloads per wave per tile
  __shared__ __align__(16) short As[2][TM][32];
  __shared__ __align__(16) short Ws[2][128][32];

  const int tid  = threadIdx.x;
  const int bm = blockIdx.x, bn = blockIdx.y;
  const int lane = tid & 63, wave = tid >> 6;
  const int n = lane & 15, quad = lane >> 4;
  const int mw = (wave >> 1) * (TM / 2), nw = (wave & 1) * 64;

  f32x4 acc[MBF][4];
#pragma unroll
  for (int mb = 0; mb < MBF; mb++)
#pragma unroll
    for (int nb = 0; nb < 4; nb++)
#pragma unroll
      for (int r = 0; r < 4; r++) acc[mb][nb][r] = 0.f;

  // staging map: per gload inst a wave writes 1024B = 16 rows x 64B.
  const int sr = lane >> 2;
  const int sc = (lane & 3) * 8;
  const short* aSrc[AIN];
#pragma unroll
  for (int i = 0; i < AIN; i++)
    aSrc[i] = A + (size_t)(bm * TM + wave * (16 * AIN) + i * 16 + sr) * lda + sc;
  const short* wSrc[2];
#pragma unroll
  for (int i = 0; i < 2; i++)
    wSrc[i] = W + (size_t)(bn * 128 + wave * 32 + i * 16 + sr) * ldw + sc;

  auto stage = [&](int buf, int kk) {
#pragma unroll
    for (int i = 0; i < AIN; i++)
      gload16(aSrc[i] + kk, &As[buf][wave * (16 * AIN) + i * 16][0]);
#pragma unroll
    for (int i = 0; i < 2; i++)
      gload16(wSrc[i] + kk, &Ws[buf][wave * 32 + i * 16][0]);
  };

  stage(0, 0);
  int cur = 0;
  for (int kk = 0; kk < K; kk += 32) {
    if (kk + 32 < K) {
      stage(cur ^ 1, kk + 32);
      asm volatile("s_waitcnt vmcnt(%0)" :: "n"(NLD) : "memory");
    } else {
      asm volatile("s_waitcnt vmcnt(0)" ::: "memory");
    }
    BARRIER0; SCHED0;            // buf[cur] ready for all waves

    bf16x8 af[MBF], bfr[4];
#pragma unroll
    for (int mb = 0; mb < MBF; mb++) af[mb] = *(bf16x8*)&As[cur][mw + mb * 16 + n][quad * 8];
#pragma unroll
    for (int nb = 0; nb < 4; nb++)   bfr[nb] = *(bf16x8*)&Ws[cur][nw + nb * 16 + n][quad * 8];
#pragma unroll
    for (int mb = 0; mb < MBF; mb++)
#pragma unroll
      for (int nb = 0; nb < 4; nb++)
        acc[mb][nb] = __builtin_amdgcn_mfma_f32_16x16x32_bf16(af[mb], bfr[nb], acc[mb][nb], 0, 0, 0);

    LGKM0; BARRIER0; SCHED0;     // all waves done reading buf[cur]
    cur ^= 1;
  }

  // ---- epilogue (MFMA C-layout: row = quad*4+r, col = n within 16x16) ----
#pragma unroll
  for (int mb = 0; mb < MBF; mb++) {
    float entv[4], rbv[4];
#pragma unroll
    for (int r = 0; r < 4; r++) {
      const int row = bm * TM + mw + mb * 16 + quad * 4 + r;
      entv[r] = ent ? ent[row] : 0.f;
      rbv[r]  = rbias ? rbias[row] : 0.f;
    }
#pragma unroll
    for (int nb = 0; nb < 4; nb++) {
      const int col = bn * 128 + nw + nb * 16 + n;
      const float bs = bias ? bias[col] : 0.f;
      const float wc = ent ? wcol[(size_t)col * wstride] : 0.f;
#pragma unroll
      for (int r = 0; r < 4; r++) {
        const int row = bm * TM + mw + mb * 16 + quad * 4 + r;
        float v = acc[mb][nb][r] + bs + rbv[r];
        if (ent)  v += entv[r] * wc;
        if (relu) v = fmaxf(v, 0.f);
        if (C32) C32[(size_t)row * ldc + col] = v;
        if (C16) C16[(size_t)row * ldc + col] = f2bf(v);
      }
    }
  }
}

// ---------------------------------------------------------------------------
// gather + fp32->bf16: dst[u][k] = bf16(node_emb[ids[u]][k])
// ---------------------------------------------------------------------------
__global__ __launch_bounds__(256)
void gather_conv_kernel(const float* __restrict__ emb, const int* __restrict__ ids,
                        short* __restrict__ dst)
{
  int idx = blockIdx.x * 256 + threadIdx.x;   // < UN*DN
  int u = idx >> 10;
  dst[idx] = f2bf(emb[(size_t)ids[u] * 1024 + (idx & 1023)]);
}

// ---------------------------------------------------------------------------
// RoPE: reads X fp32, writes bf16 xr
// ---------------------------------------------------------------------------
__global__ __launch_bounds__(256)
void rope_kernel(const float* __restrict__ x, short* __restrict__ xr,
                 const int* __restrict__ ids, const int* __restrict__ nyp)
{
  int idx = blockIdx.x * 256 + threadIdx.x;
  int u = idx >> 10, j = idx & 1023;
  int blk = j >> 9, o = j & 511;
  int i = o & 255;
  int t = ids[u];
  int ny = *nyp;
  float pos = (blk == 0) ? (float)(t / ny) : (float)(t % ny);
  float theta = expf((float)i * -0.0359778921f);   // -ln(10000)/256
  float ang = pos * theta;
  float c = cosf(ang), sn = sinf(ang);
  const float* xrow = x + (size_t)u * 1024 + blk * 512;
  float x1 = xrow[i];
  float x2 = xrow[256 + i];
  xr[idx] = f2bf((o < 256) ? (x1 * c - x2 * sn) : (x1 * sn + x2 * c));
}

// ---------------------------------------------------------------------------
// MFMA bf16 flash attention, v4: QBLK=32/wave (128 q-rows/block), V fed
// pre-transposed by the V^T GEMM, and staging via the ROUND-2-VERIFIED
// mechanism: register-staged global loads + explicit ds_write_b128 at
// XOR-swizzled addresses, single LDS buffer, T14 issue-early/write-late
// schedule with LGKM0+barrier pairs (exact r2 sync template).
// qk: bf16 [4096][2048] fused q|k; vt: bf16 [1024][4096]; o: bf16 [4096][1024].
// ---------------------------------------------------------------------------
__global__ __launch_bounds__(256)
void attn_mfma_kernel(const short* __restrict__ qk, const short* __restrict__ vt,
                      short* __restrict__ o)
{
  __shared__ __align__(16) short Kt[64][64];        // [key][d]  swizzled content
  __shared__ __align__(16) short Vt[64][64];        // [d][key]  swizzled content
  __shared__ __align__(16) short Pb[4][32][64];     // per-wave P slab, swizzled

  const int tid  = threadIdx.x;
  const int lane = tid & 63;
  const int wave = tid >> 6;

  // XCD chunk swizzle: 512 blocks, 8 XCDs -> each XCD gets 2 whole heads.
  int wg = blockIdx.x + 32 * blockIdx.y;
  wg = (wg & 7) * 64 + (wg >> 3);
  const int qb   = wg & 31;         // 128-row q block
  const int head = wg >> 5;

  const int n    = lane & 15;
  const int quad = lane >> 4;

  // staging geometry: lane covers rows {srow, srow+8} (K keys / Vt d-rows),
  // 16B chunk scb within the 128B row; swizzle byte = (row&7)<<4, identical
  // for srow and srow+8.
  const int srow = 16 * wave + (lane >> 3);
  const int scb  = (lane & 7) * 16;
  const int sdst = srow * 128 + (scb ^ ((srow & 7) << 4));

  // Q fragments: 2 q-groups of 16 rows; scale 1/8 exact (pow2)
  bf16x8 qfrag[2][2];
#pragma unroll
  for (int qg = 0; qg < 2; qg++) {
    const int qrow = qb * 128 + wave * 32 + qg * 16 + n;
    const short* qptr = qk + (size_t)qrow * 2048 + head * 64 + quad * 8;
#pragma unroll
    for (int c = 0; c < 2; c++)
#pragma unroll
      for (int j = 0; j < 8; j++)
        qfrag[qg][c][j] = f2bf(bf2f(qptr[c * 32 + j]) * 0.125f);
  }

  float m_r[2][4], l_r[2][4];       // deferred per-lane l partials
  f32x4 o_acc[2][4];
#pragma unroll
  for (int qg = 0; qg < 2; qg++)
#pragma unroll
    for (int r = 0; r < 4; r++) { m_r[qg][r] = -3.0e38f; l_r[qg][r] = 0.f; }
#pragma unroll
  for (int qg = 0; qg < 2; qg++)
#pragma unroll
    for (int nb = 0; nb < 4; nb++)
#pragma unroll
      for (int r = 0; r < 4; r++) o_acc[qg][nb][r] = 0.f;

  char* KtB = (char*)&Kt[0][0];
  char* VtB = (char*)&Vt[0][0];
  char* PbB = (char*)&Pb[wave][0][0];

  auto loadT = [&](int kt, bf16x8& k0, bf16x8& k1, bf16x8& v0, bf16x8& v1) {
    const char* kp = (const char*)(qk + (size_t)(kt * 64 + srow) * 2048
                                   + 1024 + head * 64) + scb;
    k0 = *(const bf16x8*)(kp);
    k1 = *(const bf16x8*)(kp + 8 * 2048 * 2);     // +8 key rows
    const char* vp = (const char*)(vt + (size_t)(head * 64 + srow) * 4096
                                   + kt * 64) + scb;
    v0 = *(const bf16x8*)(vp);
    v1 = *(const bf16x8*)(vp + 8 * 4096 * 2);     // +8 d rows
  };

  auto writeT = [&](bf16x8 k0, bf16x8 k1, bf16x8 v0, bf16x8 v1) {
    *(bf16x8*)(KtB + sdst)        = k0;
    *(bf16x8*)(KtB + sdst + 1024) = k1;           // +8 rows * 128B
    *(bf16x8*)(VtB + sdst)        = v0;
    *(bf16x8*)(VtB + sdst + 1024) = v1;
  };

  auto computeT = [&]() {
    // ---- QK^T (K frags shared across both q-groups) ----
    f32x4 s[2][4];
#pragma unroll
    for (int nb = 0; nb < 4; nb++) {
      const int row = nb * 16 + n;
      const int rx = (row & 7) << 4;
      bf16x8 k0 = *(bf16x8*)(KtB + row * 128 + ((16 * quad) ^ rx));
      bf16x8 k1 = *(bf16x8*)(KtB + row * 128 + ((64 + 16 * quad) ^ rx));
      __builtin_amdgcn_s_setprio(1);
#pragma unroll
      for (int qg = 0; qg < 2; qg++) {
        f32x4 z = {0.f, 0.f, 0.f, 0.f};
        z = __builtin_amdgcn_mfma_f32_16x16x32_bf16(qfrag[qg][0], k0, z, 0, 0, 0);
        z = __builtin_amdgcn_mfma_f32_16x16x32_bf16(qfrag[qg][1], k1, z, 0, 0, 0);
        s[qg][nb] = z;
      }
      __builtin_amdgcn_s_setprio(0);
    }

    // ---- online softmax, deferred max (THR=8), deferred l-sum ----
#pragma unroll
    for (int qg = 0; qg < 2; qg++) {
      float tl[4];
#pragma unroll
      for (int r = 0; r < 4; r++)
        tl[r] = fmaxf(fmaxf(s[qg][0][r], s[qg][1][r]), fmaxf(s[qg][2][r], s[qg][3][r]));
      bool grow = (tl[0] > m_r[qg][0] + 8.f) || (tl[1] > m_r[qg][1] + 8.f) ||
                  (tl[2] > m_r[qg][2] + 8.f) || (tl[3] > m_r[qg][3] + 8.f);
      if (__any(grow)) {
#pragma unroll
        for (int r = 0; r < 4; r++) {
          float t = tl[r];
          t = fmaxf(t, __shfl_xor(t, 1));
          t = fmaxf(t, __shfl_xor(t, 2));
          t = fmaxf(t, __shfl_xor(t, 4));
          t = fmaxf(t, __shfl_xor(t, 8));
          float mnew = fmaxf(m_r[qg][r], t);
          float al = __expf(m_r[qg][r] - mnew);
          m_r[qg][r] = mnew;
          l_r[qg][r] *= al;
#pragma unroll
          for (int nb = 0; nb < 4; nb++) o_acc[qg][nb][r] *= al;
        }
      }

#pragma unroll
      for (int nb = 0; nb < 4; nb++) {
        float p0 = __expf(s[qg][nb][0] - m_r[qg][0]);
        float p1 = __expf(s[qg][nb][1] - m_r[qg][1]);
        float p2 = __expf(s[qg][nb][2] - m_r[qg][2]);
        float p3 = __expf(s[qg][nb][3] - m_r[qg][3]);
        l_r[qg][0] += p0; l_r[qg][1] += p1; l_r[qg][2] += p2; l_r[qg][3] += p3;
        unsigned u01, u23;
        asm("v_cvt_pk_bf16_f32 %0, %1, %2" : "=v"(u01) : "v"(p0), "v"(p1));
        asm("v_cvt_pk_bf16_f32 %0, %1, %2" : "=v"(u23) : "v"(p2), "v"(p3));
        const int colb = 2 * (nb * 16 + n);
        const int r0 = qg * 16 + quad * 4;
        *(short*)(PbB + (r0 + 0) * 128 + (colb ^ (((r0 + 0) & 7) << 4))) = (short)(u01 & 0xffff);
        *(short*)(PbB + (r0 + 1) * 128 + (colb ^ (((r0 + 1) & 7) << 4))) = (short)(u01 >> 16);
        *(short*)(PbB + (r0 + 2) * 128 + (colb ^ (((r0 + 2) & 7) << 4))) = (short)(u23 & 0xffff);
        *(short*)(PbB + (r0 + 3) * 128 + (colb ^ (((r0 + 3) & 7) << 4))) = (short)(u23 >> 16);
      }
    }

    // ---- PV (V frags shared across both q-groups) ----
#pragma unroll
    for (int c = 0; c < 2; c++) {
      const int prx = (n & 7) << 4;
      bf16x8 pf0 = *(bf16x8*)(PbB + n * 128 + ((64 * c + 16 * quad) ^ prx));
      bf16x8 pf1 = *(bf16x8*)(PbB + (16 + n) * 128 + ((64 * c + 16 * quad) ^ prx));
#pragma unroll
      for (int nb = 0; nb < 4; nb++) {
        const int vrow = nb * 16 + n;
        const int vrx = (vrow & 7) << 4;
        bf16x8 vf = *(bf16x8*)(VtB + vrow * 128 + ((64 * c + 16 * quad) ^ vrx));
        __builtin_amdgcn_s_setprio(1);
        o_acc[0][nb] = __builtin_amdgcn_mfma_f32_16x16x32_bf16(pf0, vf, o_acc[0][nb], 0, 0, 0);
        o_acc[1][nb] = __builtin_amdgcn_mfma_f32_16x16x32_bf16(pf1, vf, o_acc[1][nb], 0, 0, 0);
        __builtin_amdgcn_s_setprio(0);
      }
    }
  };

  // ---- T14 pipelined main loop (unroll x2 for static dual regsets) ----
  bf16x8 ka0, ka1, va0, va1, kb0, kb1, vb0, vb1;
  loadT(0, ka0, ka1, va0, va1);
  for (int kt = 0; kt < 64; kt += 2) {
    LGKM0; BARRIER0; SCHED0;          // all waves done reading prev tile
    writeT(ka0, ka1, va0, va1);       // vmcnt waits on A-regs inserted here
    loadT(kt + 1, kb0, kb1, vb0, vb1);
    LGKM0; BARRIER0; SCHED0;          // tile kt visible in LDS
    computeT();

    LGKM0; BARRIER0; SCHED0;
    writeT(kb0, kb1, vb0, vb1);
    if (kt + 2 < 64) loadT(kt + 2, ka0, ka1, va0, va1);
    LGKM0; BARRIER0; SCHED0;
    computeT();
  }

  // final l reduction (deferred) + output
#pragma unroll
  for (int qg = 0; qg < 2; qg++)
#pragma unroll
    for (int r = 0; r < 4; r++) {
      float t = l_r[qg][r];
      t += __shfl_xor(t, 1); t += __shfl_xor(t, 2);
      t += __shfl_xor(t, 4); t += __shfl_xor(t, 8);
      l_r[qg][r] = 1.f / t;
    }
#pragma unroll
  for (int qg = 0; qg < 2; qg++)
#pragma unroll
    for (int nb = 0; nb < 4; nb++)
#pragma unroll
      for (int r = 0; r < 4; r++) {
        int row = qb * 128 + wave * 32 + qg * 16 + quad * 4 + r;
        o[(size_t)row * 1024 + head * 64 + nb * 16 + n] = f2bf(o_acc[qg][nb][r] * l_r[qg][r]);
      }
}

// ---------------------------------------------------------------------------
// x = LayerNorm(x + delta)*g + b, in place; also writes bf16 copy xb
// ---------------------------------------------------------------------------
__global__ __launch_bounds__(256)
void add_ln_kernel(float* __restrict__ x, const float* __restrict__ d,
                   const float* __restrict__ g, const float* __restrict__ b,
                   short* __restrict__ xb)
{
  __shared__ float sb[4];
  const int row = blockIdx.x, tid = threadIdx.x;
  float* xr = x + (size_t)row * 1024;
  const float* dr = d + (size_t)row * 1024;

  float v[4]; float s = 0.f, ss = 0.f;
#pragma unroll
  for (int i = 0; i < 4; i++) {
    int c = tid + 256 * i;
    v[i] = xr[c] + dr[c];
    s += v[i]; ss += v[i] * v[i];
  }
#pragma unroll
  for (int off = 32; off; off >>= 1) { s += __shfl_down(s, off); ss += __shfl_down(ss, off); }
  const int lane = tid & 63, wid = tid >> 6;
  if (lane == 0) sb[wid] = s;
  __syncthreads();
  s = sb[0] + sb[1] + sb[2] + sb[3];
  __syncthreads();
  if (lane == 0) sb[wid] = ss;
  __syncthreads();
  ss = sb[0] + sb[1] + sb[2] + sb[3];

  float mean = s * (1.f / 1024.f);
  float var  = ss * (1.f / 1024.f) - mean * mean;
  float inv  = rsqrtf(var + 1e-5f);
#pragma unroll
  for (int i = 0; i < 4; i++) {
    int c = tid + 256 * i;
    float o = (v[i] - mean) * inv * g[c] + b[c];
    xr[c] = o;
    xb[(size_t)row * 1024 + c] = f2bf(o);
  }
}

// ---------------------------------------------------------------------------
// logits + softmax/entropy (unchanged, fp32)
// ---------------------------------------------------------------------------
__global__ __launch_bounds__(256)
void logits_kernel(const float* __restrict__ h1, const float* __restrict__ w2,
                   const float* __restrict__ b2, float* __restrict__ out)
{
  const int lane = threadIdx.x & 63;
  const int row = blockIdx.x * 4 + (threadIdx.x >> 6);
  const float* hr = h1 + (size_t)row * 512;
  float s = 0.f;
#pragma unroll
  for (int i = 0; i < 8; i++) s += hr[lane + 64 * i] * w2[lane + 64 * i];
#pragma unroll
  for (int off = 32; off; off >>= 1) s += __shfl_down(s, off);
  if (lane == 0) {
    out[4097 + row] = s + b2[0];
  }
}

__global__ __launch_bounds__(1024)
void softmax_entropy_kernel(const float* __restrict__ lg, float* __restrict__ out)
{
  __shared__ float sb[16];
  const int tid = threadIdx.x;
  const int lane = tid & 63, wid = tid >> 6;

  float l0[4];
#pragma unroll
  for (int i = 0; i < 4; i++) l0[i] = lg[tid + 1024 * i];

  float mx = fmaxf(fmaxf(l0[0], l0[1]), fmaxf(l0[2], l0[3]));
#pragma unroll
  for (int off = 32; off; off >>= 1) mx = fmaxf(mx, __shfl_down(mx, off));
  if (lane == 0) sb[wid] = mx;
  __syncthreads();
  if (tid == 0) { float m = sb[0]; for (int i = 1; i < 16; i++) m = fmaxf(m, sb[i]); sb[0] = m; }
  __syncthreads();
  mx = sb[0];
  __syncthreads();

  float e[4], s = 0.f;
#pragma unroll
  for (int i = 0; i < 4; i++) { e[i] = expf(l0[i] - mx); s += e[i]; }
#pragma unroll
  for (int off = 32; off; off >>= 1) s += __shfl_down(s, off);
  if (lane == 0) sb[wid] = s;
  __syncthreads();
  if (tid == 0) { float t = 0.f; for (int i = 0; i < 16; i++) t += sb[i]; sb[0] = t; }
  __syncthreads();
  float inv = 1.f / sb[0];
  __syncthreads();

  float h = 0.f;
#pragma unroll
  for (int i = 0; i < 4; i++) {
    float p = e[i] * inv;
    out[tid + 1024 * i] = p;
    h += p * logf(p + 1e-12f);
  }
#pragma unroll
  for (int off = 32; off; off >>= 1) h += __shfl_down(h, off);
  if (lane == 0) sb[wid] = h;
  __syncthreads();
  if (tid == 0) { float t = 0.f; for (int i = 0; i < 16; i++) t += sb[i]; out[4096] = -t; }
}

// ---------------------------------------------------------------------------
extern "C" void kernel_launch(void* const* d_in, const int* in_sizes, int n_in,
                              void* d_out, int out_size, void* d_ws, size_t ws_size,
                              hipStream_t stream)
{
  const float* node_emb   = (const float*)d_in[0];
  const int*   tile_ids   = (const int*)d_in[1];
  const float* entropies  = (const float*)d_in[2];
  const int*   Ny_p       = (const int*)d_in[3];
  const float* in_w       = (const float*)d_in[4];
  const float* in_b       = (const float*)d_in[5];
  const float* attn_in_w  = (const float*)d_in[6];
  const float* attn_in_b  = (const float*)d_in[7];
  const float* attn_out_w = (const float*)d_in[8];
  const float* attn_out_b = (const float*)d_in[9];
  const float* ff_w1      = (const float*)d_in[10];
  const float* ff_b1      = (const float*)d_in[11];
  const float* ff_w2      = (const float*)d_in[12];
  const float* ff_b2      = (const float*)d_in[13];
  const float* ln1_g      = (const float*)d_in[14];
  const float* ln1_b      = (const float*)d_in[15];
  const float* ln2_g      = (const float*)d_in[16];
  const float* ln2_b      = (const float*)d_in[17];
  const float* sh_w0      = (const float*)d_in[18];
  const float* sh_b0      = (const float*)d_in[19];
  const float* sh_w1      = (const float*)d_in[20];
  const float* sh_b1      = (const float*)d_in[21];
  const float* sh_w2      = (const float*)d_in[22];
  const float* sh_b2      = (const float*)d_in[23];
  float* out = (float*)d_out;

  // Workspace (byte offsets; peak 88 MB).
  char* w8 = (char*)d_ws;
  float* X    = (float*)(w8);                        // [0,16M)  fp32 x, persistent
  short* Xb   = (short*)(w8 + (16u << 20));          // [16,24M) bf16 x
  short* XRb  = (short*)(w8 + (24u << 20));          // [24,32M) bf16 rope(x); later H0b
  short* QKb  = (short*)(w8 + (32u << 20));          // [32,48M) bf16 q|k; later Hb, H1
  short* Vb   = (short*)(w8 + (48u << 20));          // [48,56M) bf16 V^T [1024][4096]
  short* Ob   = (short*)(w8 + (56u << 20));          // [56,64M) bf16 attn out; also A0b
  float* O2   = (float*)(w8 + (64u << 20));          // [64,80M) fp32 out-proj / ffn-out
  short* Wb   = (short*)(w8 + (80u << 20));          // [80,88M) bf16 weight scratch (JIT)
  short* Hb   = QKb;
  short* A0b  = Ob;
  short* H0b  = XRb;
  float* H1   = (float*)(w8 + (32u << 20));

  // gather + convert node_emb rows
  gather_conv_kernel<<<UN * DN / 256, 256, 0, stream>>>(node_emb, tile_ids, A0b);

  // x = [gather, entropies] @ in_w.T + in_b  (K=1024 MFMA + rank-1 entropy col)
  convw_in_kernel<<<DN * DN / 256, 256, 0, stream>>>(in_w, Wb);
  gemm_bf16<64><<<dim3(64, 8), 256, 0, stream>>>(A0b, 1024, Wb, 1024, in_b,
      X, Xb, 1024, 1024, 0, entropies, in_w + 1024, 1025, nullptr);

  for (int l = 0; l < LN_; l++) {
    const float* b_qkv = attn_in_b + (size_t)l * 3 * DN;

    convw_kernel<<<3 * DN * DN / 2048, 256, 0, stream>>>(attn_in_w + (size_t)l * 3 * DN * DN, Wb);
    rope_kernel<<<UN * DN / 256, 256, 0, stream>>>(X, XRb, tile_ids, Ny_p);
    // q|k fused (N=2048)
    gemm_bf16<128><<<dim3(32, 16), 256, 0, stream>>>(XRb, 1024, Wb, 1024, b_qkv,
        nullptr, QKb, 2048, 1024, 0, nullptr, nullptr, 0, nullptr);
    // V^T[d][u] = sum_k wv[d][k] x[u][k] + bv[d]  (swapped-operand GEMM)
    gemm_bf16<64><<<dim3(16, 32), 256, 0, stream>>>(Wb + (size_t)2048 * 1024, 1024,
        Xb, 1024, nullptr, nullptr, Vb, 4096, 1024, 0, nullptr, nullptr, 0, b_qkv + 2048);
    attn_mfma_kernel<<<dim3(32, HN), 256, 0, stream>>>(QKb, Vb, Ob);
    convw_kernel<<<DN * DN / 2048, 256, 0, stream>>>(attn_out_w + (size_t)l * DN * DN, Wb);
    gemm_bf16<64><<<dim3(64, 8), 256, 0, stream>>>(Ob, 1024, Wb, 1024,
        attn_out_b + (size_t)l * DN, O2, nullptr, 1024, 1024, 0, nullptr, nullptr, 0, nullptr);
    add_ln_kernel<<<UN, 256, 0, stream>>>(X, O2, ln1_g + (size_t)l * DN, ln1_b + (size_t)l * DN, Xb);
    convw_kernel<<<2 * DN * DN / 2048, 256, 0, stream>>>(ff_w1 + (size_t)l * 2 * DN * DN, Wb);
    gemm_bf16<128><<<dim3(32, 16), 256, 0, stream>>>(Xb, 1024, Wb, 1024,
        ff_b1 + (size_t)l * 2 * DN, nullptr, Hb, 2048, 1024, 1, nullptr, nullptr, 0, nullptr);
    convw_kernel<<<2 * DN * DN / 2048, 256, 0, stream>>>(ff_w2 + (size_t)l * DN * 2 * DN, Wb);
    gemm_bf16<64><<<dim3(64, 8), 256, 0, stream>>>(Hb, 2048, Wb, 2048,
        ff_b2 + (size_t)l * DN, O2, nullptr, 1024, 2048, 0, nullptr, nullptr, 0, nullptr);
    add_ln_kernel<<<UN, 256, 0, stream>>>(X, O2, ln2_g + (size_t)l * DN, ln2_b + (size_t)l * DN, Xb);
  }

  // head MLP
  convw_kernel<<<512 * DN / 2048, 256, 0, stream>>>(sh_w0, Wb);
  gemm_bf16<64><<<dim3(64, 4), 256, 0, stream>>>(Xb, 1024, Wb, 1024, sh_b0,
      nullptr, H0b, 512, 1024, 1, nullptr, nullptr, 0, nullptr);
  convw_kernel<<<512 * 512 / 2048, 256, 0, stream>>>(sh_w1, Wb);
  gemm_bf16<64><<<dim3(64, 4), 256, 0, stream>>>(H0b, 512, Wb, 512, sh_b1,
      H1, nullptr, 512, 512, 1, nullptr, nullptr, 0, nullptr);
  logits_kernel<<<UN / 4, 256, 0, stream>>>(H1, sh_w2, sh_b2, out);
  softmax_entropy_kernel<<<1, 1024, 0, stream>>>(out + 4097, out);
}